// Round 1
// 315.612 us; speedup vs baseline: 1.0489x; 1.0489x over previous
//
#include <hip/hip_runtime.h>
#include <hip/hip_bf16.h>

#define N_NODES 50000
#define N_EDGES 640000
#define HID 128

typedef unsigned short ushort_t;
typedef __attribute__((ext_vector_type(8))) short bf16x8;   // 8 bf16 = 4 VGPR (MFMA A/B frag)
typedef __attribute__((ext_vector_type(4))) float f32x4;    // MFMA C/D frag

// ws layout (ushort units from base):
//   maggr  [0,        6400000)   bf16 N x 128 (pk-atomic accumulated)
//   hb     [6400000, 12800000)   bf16 N x 128 (h pre-converted)
//   w1b    [12800000,12832768)   Wab 256 x 128: rows 0..127 = ew1[:,0:128] (A), rows 128..255 = ew1[:,128:256] (B)
//   w2b    [12832768,12849152)   128 x 128
//   w3b    [12849152,12865536)   128 x 128
//   c1b    [12865536,12881920)   128 x 128
//   n1b    [12881920,12914688)   128 x 256
//   n2b    [12914688,12931072)   128 x 128
//   n3b    [12931072,12947456)   128 x 128
//   w1d2   (float*) at ushort 12947456, 128 f32 = ew1[:,256]
// AB table (bf16 N x 256 = 25.6 MB) lives in d_out's hout region (dead until node_kernel
// fully overwrites it): A[n] = h@W1a^T in feats 0..127, B[n] = h@W1b^T + eb1 in feats 128..255.
#define U_MAGGR 0
#define U_HB    6400000
#define U_W1B   12800000
#define U_W2B   12832768
#define U_W3B   12849152
#define U_C1B   12865536
#define U_N1B   12881920
#define U_N2B   12914688
#define U_N3B   12931072
#define U_W1D2  12947456

// silu via exp2 + fast rcp (bf16-output tolerance; saves div fixup sequence)
__device__ __forceinline__ float silu_f(float v) {
    const float e = __builtin_amdgcn_exp2f(v * -1.442695041f);
    return v * __builtin_amdgcn_rcpf(1.0f + e);
}

__device__ __forceinline__ ushort_t f2b(float f) {
    __hip_bfloat16 b = __float2bfloat16(f);          // RNE
    return __builtin_bit_cast(ushort_t, b);
}
__device__ __forceinline__ float b2f(ushort_t u) {
    union { float f; unsigned int i; } v; v.i = ((unsigned int)u) << 16; return v.f;
}
__device__ __forceinline__ float u2f(unsigned int u) {
    union { float f; unsigned int i; } v; v.i = u; return v.f;
}
__device__ __forceinline__ unsigned int pack2(float a, float b) {
    return (unsigned int)f2b(a) | ((unsigned int)f2b(b) << 16);
}
// uint4 of 8 bf16 -> 8 f32 (1 VALU op each: shl or and)
__device__ __forceinline__ void up8(const uint4& u, float* f) {
    f[0] = u2f(u.x << 16); f[1] = u2f(u.x & 0xffff0000u);
    f[2] = u2f(u.y << 16); f[3] = u2f(u.y & 0xffff0000u);
    f[4] = u2f(u.z << 16); f[5] = u2f(u.z & 0xffff0000u);
    f[6] = u2f(u.w << 16); f[7] = u2f(u.w & 0xffff0000u);
}
__device__ __forceinline__ void atom_add_f32(float* p, float v) { unsafeAtomicAdd(p, v); }

// packed bf16x2 atomic add (gfx950: global_atomic_pk_add_bf16)
__device__ __forceinline__ void atom_pk_bf16(ushort_t* p, unsigned int v) {
#if __has_builtin(__builtin_amdgcn_global_atomic_fadd_v2bf16)
    typedef __attribute__((ext_vector_type(2))) short s2;
    s2 sv = __builtin_bit_cast(s2, v);
    __builtin_amdgcn_global_atomic_fadd_v2bf16((__attribute__((address_space(1))) s2*)p, sv);
#else
    unsigned int* up = (unsigned int*)p;
    unsigned int old = __hip_atomic_load(up, __ATOMIC_RELAXED, __HIP_MEMORY_SCOPE_AGENT), assumed;
    do {
        assumed = old;
        float lo = b2f((ushort_t)(assumed & 0xffff)) + b2f((ushort_t)(v & 0xffff));
        float hi = b2f((ushort_t)(assumed >> 16)) + b2f((ushort_t)(v >> 16));
        unsigned int nv = (unsigned int)f2b(lo) | ((unsigned int)f2b(hi) << 16);
        old = atomicCAS(up, assumed, nv);
    } while (old != assumed);
#endif
}

// ---------------- prep ----------------
__global__ void prep_kernel(const float* __restrict__ x, const float* __restrict__ h,
                            const float* __restrict__ ew1, const float* __restrict__ ew2,
                            const float* __restrict__ ew3, const float* __restrict__ cw1,
                            const float* __restrict__ nw1, const float* __restrict__ nw2,
                            const float* __restrict__ nw3,
                            ushort_t* __restrict__ wsu, float* __restrict__ xout) {
    long i = (long)blockIdx.x * 256 + threadIdx.x;
    if (i < 3200000) { ((unsigned int*)(wsu + U_MAGGR))[i] = 0u; return; }
    i -= 3200000;
    if (i < 3200000) { ((unsigned int*)(wsu + U_HB))[i] = pack2(h[2 * i], h[2 * i + 1]); return; }
    i -= 3200000;
    if (i < 32768) {
        // Wab[f][k]: f<128 -> ew1[f][k] (A half), f>=128 -> ew1[f-128][128+k] (B half)
        const int f = (int)(i >> 7);
        const int k = (int)(i & 127);
        const int src = (f < 128) ? (f * 257 + k) : ((f - 128) * 257 + 128 + k);
        wsu[U_W1B + i] = f2b(ew1[src]);
        return;
    }
    i -= 32768;
    if (i < 16384) { wsu[U_W2B + i] = f2b(ew2[i]); return; }
    i -= 16384;
    if (i < 16384) { wsu[U_W3B + i] = f2b(ew3[i]); return; }
    i -= 16384;
    if (i < 16384) { wsu[U_C1B + i] = f2b(cw1[i]); return; }
    i -= 16384;
    if (i < 32768) { wsu[U_N1B + i] = f2b(nw1[i]); return; }
    i -= 32768;
    if (i < 16384) { wsu[U_N2B + i] = f2b(nw2[i]); return; }
    i -= 16384;
    if (i < 16384) { wsu[U_N3B + i] = f2b(nw3[i]); return; }
    i -= 16384;
    if (i < 128) { ((float*)(wsu + U_W1D2))[i] = ew1[i * 257 + 256]; return; }
    i -= 128;
    if (i < 150000) xout[i] = x[i];
}

// ---------------- AB precompute: AB[n] = [h@W1a^T | h@W1b^T + eb1] ----------------
// 64 nodes/block, 4 waves; wave owns 64 of 256 output feats. K=128. ~3.3 GF total.
__global__ __launch_bounds__(256, 4) void ab_kernel(
    const ushort_t* __restrict__ hb, const ushort_t* __restrict__ wab,
    const float* __restrict__ eb1, ushort_t* __restrict__ abp) {
    __shared__ ushort_t sH[8192];   // [64][128] bf16, XOR-swizzled
    const int t = threadIdx.x;
    const int lane = t & 63;
    const int wid = t >> 6;          // 0..3
    const int r15 = lane & 15;
    const int khi = lane >> 4;
    const int rhi = khi * 4;
    const int fb = wid * 64;         // 64 feats per wave (4 row-blocks)
    const int n0 = blockIdx.x * 64;

    const uint4* hb4 = (const uint4*)hb;
#pragma unroll
    for (int it = 0; it < 4; ++it) {
        const int idx = it * 256 + t;          // 1024 tasks: 64 nodes x 16 chunks
        const int e = idx >> 4, c = idx & 15;
        const int n = n0 + e;
        uint4 v = make_uint4(0u, 0u, 0u, 0u);
        if (n < N_NODES) v = hb4[(size_t)n * 16 + c];
        const int ui = (e * 128 + c * 8) ^ ((e & 7) << 3);
        *(uint4*)(sH + ui) = v;
    }
    __syncthreads();

    f32x4 acc[4][4];
#pragma unroll
    for (int mi = 0; mi < 4; ++mi)
#pragma unroll
        for (int ni = 0; ni < 4; ++ni) acc[mi][ni] = (f32x4){0.f, 0.f, 0.f, 0.f};
#pragma unroll
    for (int ks = 0; ks < 4; ++ks) {
        bf16x8 a[4];
#pragma unroll
        for (int mi = 0; mi < 4; ++mi)
            a[mi] = *(const bf16x8*)(wab + (fb + mi * 16 + r15) * 128 + ks * 32 + khi * 8);
        bf16x8 b[4];
#pragma unroll
        for (int ni = 0; ni < 4; ++ni) {
            const int e = ni * 16 + r15;
            const int ui = (e * 128 + ks * 32 + khi * 8) ^ ((e & 7) << 3);
            b[ni] = *(const bf16x8*)(sH + ui);
        }
#pragma unroll
        for (int mi = 0; mi < 4; ++mi)
#pragma unroll
            for (int ni = 0; ni < 4; ++ni)
                acc[mi][ni] = __builtin_amdgcn_mfma_f32_16x16x32_bf16(a[mi], b[ni], acc[mi][ni], 0, 0, 0);
    }

#pragma unroll
    for (int mi = 0; mi < 4; ++mi) {
        const int f0 = fb + mi * 16 + rhi;     // entire 16-block is on one side of 128
        float4 bb = make_float4(0.f, 0.f, 0.f, 0.f);
        if (f0 >= 128) bb = *(const float4*)&eb1[f0 - 128];
#pragma unroll
        for (int ni = 0; ni < 4; ++ni) {
            const int n = n0 + ni * 16 + r15;
            if (n < N_NODES) {
                *(uint2*)(abp + (size_t)n * 256 + f0) =
                    make_uint2(pack2(acc[mi][ni][0] + bb.x, acc[mi][ni][1] + bb.y),
                               pack2(acc[mi][ni][2] + bb.z, acc[mi][ni][3] + bb.w));
            }
        }
    }
}

// swapped dense layer, K=128: D[feat][edge] = W(128x128) x act^T.
// 8 waves: wave wid owns 16 output feats (fb = wid*16) x 64 edges.
// src rows: [64 edges][128 ushorts], XOR-swizzled ^((edge&7)<<3) (ushort units).
template <bool ACT>
__device__ __forceinline__ void dense128(ushort_t* sE, int srcBase, int dstBase,
                                         const ushort_t* __restrict__ W,
                                         const float* __restrict__ bias,
                                         int r15, int khi, int rhi, int fb) {
    f32x4 acc[4];
#pragma unroll
    for (int ni = 0; ni < 4; ++ni) acc[ni] = (f32x4){0.f, 0.f, 0.f, 0.f};
#pragma unroll
    for (int ks = 0; ks < 4; ++ks) {
        const bf16x8 a0 = *(const bf16x8*)(W + (fb + r15) * 128 + ks * 32 + khi * 8);
        bf16x8 b[4];
#pragma unroll
        for (int ni = 0; ni < 4; ++ni) {
            const int edge = ni * 16 + r15;
            const int ui = (srcBase + edge * 128 + ks * 32 + khi * 8) ^ ((edge & 7) << 3);
            b[ni] = *(const bf16x8*)(sE + ui);
        }
#pragma unroll
        for (int ni = 0; ni < 4; ++ni)
            acc[ni] = __builtin_amdgcn_mfma_f32_16x16x32_bf16(a0, b[ni], acc[ni], 0, 0, 0);
    }
    const float4 bb = *(const float4*)&bias[fb + rhi];
#pragma unroll
    for (int ni = 0; ni < 4; ++ni) {
        const int edge = ni * 16 + r15;
        float v0 = acc[ni][0] + bb.x;
        float v1 = acc[ni][1] + bb.y;
        float v2 = acc[ni][2] + bb.z;
        float v3 = acc[ni][3] + bb.w;
        if (ACT) { v0 = silu_f(v0); v1 = silu_f(v1); v2 = silu_f(v2); v3 = silu_f(v3); }
        const int ui = (dstBase + edge * 128 + fb + rhi) ^ ((edge & 7) << 3);
        *(uint2*)(sE + ui) = make_uint2(pack2(v0, v1), pack2(v2, v3));
    }
}

// ---------------- edge ----------------
// 512 threads / 8 waves per block, 64 edges per block -> 4 blocks/CU (LDS-bound).
// L1 of edge MLP is hoisted to ab_kernel: act1 = silu(A[src] + B[dst] + d2*w1d2).
__global__ __launch_bounds__(512, 8) void edge_kernel(
    const float* __restrict__ x, const ushort_t* __restrict__ ab,
    const int* __restrict__ ei,
    const float* __restrict__ w1d2,
    const ushort_t* __restrict__ w2b, const float* __restrict__ eb2,
    const ushort_t* __restrict__ w3b, const float* __restrict__ eb3,
    const ushort_t* __restrict__ c1b, const float* __restrict__ cb1,
    const float* __restrict__ cw2, const float* __restrict__ cb2,
    float* __restrict__ xout, ushort_t* __restrict__ maggr) {
    __shared__ ushort_t sE[16384];   // 32 KB: two [64][128] act buffers @0 and @8192
    __shared__ float srel[64][3];
    __shared__ float sd2[64];
    __shared__ int ssrc[64];
    __shared__ int sdst[64];

    const int t = threadIdx.x;
    const int lane = t & 63;
    const int wid = t >> 6;          // 0..7
    const int r15 = lane & 15;
    const int khi = lane >> 4;       // 0..3
    const int rhi = khi * 4;
    const int fb = wid * 16;         // 16 feats per wave
    const int e0 = blockIdx.x * 64;

    if (t < 64) {
        const int s = ei[e0 + t], d = ei[N_EDGES + e0 + t];
        ssrc[t] = s; sdst[t] = d;
        const float rx = x[3 * s] - x[3 * d];
        const float ry = x[3 * s + 1] - x[3 * d + 1];
        const float rz = x[3 * s + 2] - x[3 * d + 2];
        srel[t][0] = rx; srel[t][1] = ry; srel[t][2] = rz;
        sd2[t] = rx * rx + ry * ry + rz * rz;
    }
    __syncthreads();

    // stage act1 = silu(A[src] + B[dst] + d2*w1d2)  (eb1 folded into B)
    // 1024 tasks = 64 edges x 16 feat-chunks of 8; 2 tasks/thread.
    {
        const uint4* ab4 = (const uint4*)ab;
        uint4 va[2], vb[2];
        int ui[2], cc[2];
        float dd[2];
#pragma unroll
        for (int it = 0; it < 2; ++it) {
            const int idx = it * 512 + t;
            const int e = idx >> 4, c = idx & 15;
            va[it] = ab4[(size_t)ssrc[e] * 32 + c];         // A half of AB[src]
            vb[it] = ab4[(size_t)sdst[e] * 32 + 16 + c];    // B half of AB[dst]
            dd[it] = sd2[e];
            cc[it] = c;
            ui[it] = (e * 128 + c * 8) ^ ((e & 7) << 3);
        }
#pragma unroll
        for (int it = 0; it < 2; ++it) {
            const int c8 = cc[it] * 8;
            const float4 w0 = *(const float4*)&w1d2[c8];
            const float4 w1 = *(const float4*)&w1d2[c8 + 4];
            const float d2 = dd[it];
            float fa[8], fbv[8];
            up8(va[it], fa);
            up8(vb[it], fbv);
            const float v0 = silu_f(fmaf(d2, w0.x, fa[0] + fbv[0]));
            const float v1 = silu_f(fmaf(d2, w0.y, fa[1] + fbv[1]));
            const float v2 = silu_f(fmaf(d2, w0.z, fa[2] + fbv[2]));
            const float v3 = silu_f(fmaf(d2, w0.w, fa[3] + fbv[3]));
            const float v4 = silu_f(fmaf(d2, w1.x, fa[4] + fbv[4]));
            const float v5 = silu_f(fmaf(d2, w1.y, fa[5] + fbv[5]));
            const float v6 = silu_f(fmaf(d2, w1.z, fa[6] + fbv[6]));
            const float v7 = silu_f(fmaf(d2, w1.w, fa[7] + fbv[7]));
            uint4 st;
            st.x = pack2(v0, v1); st.y = pack2(v2, v3);
            st.z = pack2(v4, v5); st.w = pack2(v6, v7);
            *(uint4*)(sE + ui[it]) = st;
        }
    }
    __syncthreads();

    dense128<true >(sE, 0, 8192, w2b, eb2, r15, khi, rhi, fb);   // act1 -> act2
    __syncthreads();
    dense128<false>(sE, 8192, 0, w3b, eb3, r15, khi, rhi, fb);   // act2 -> m_ij @0
    __syncthreads();
    dense128<true >(sE, 0, 8192, c1b, cb1, r15, khi, rhi, fb);   // m_ij -> c1 @8192
    __syncthreads();

    // coord coefficient: 8 edges/wave, 8 k-groups of 16 per lane-subgroup
    {
        const int esub = lane & 7;
        const int kg = lane >> 3;             // 0..7
        const int edge = wid * 8 + esub;
        float sum = 0.f;
#pragma unroll
        for (int cc = 0; cc < 2; ++cc) {
            const int k = kg * 16 + cc * 8;
            const int ui = (8192 + edge * 128 + k) ^ (esub << 3);
            const bf16x8 v = *(const bf16x8*)(sE + ui);
            const float4 ca = *(const float4*)&cw2[k];
            const float4 cb = *(const float4*)&cw2[k + 4];
            sum = fmaf(b2f((ushort_t)v[0]), ca.x, sum);
            sum = fmaf(b2f((ushort_t)v[1]), ca.y, sum);
            sum = fmaf(b2f((ushort_t)v[2]), ca.z, sum);
            sum = fmaf(b2f((ushort_t)v[3]), ca.w, sum);
            sum = fmaf(b2f((ushort_t)v[4]), cb.x, sum);
            sum = fmaf(b2f((ushort_t)v[5]), cb.y, sum);
            sum = fmaf(b2f((ushort_t)v[6]), cb.z, sum);
            sum = fmaf(b2f((ushort_t)v[7]), cb.w, sum);
        }
        sum += __shfl_xor(sum, 8);
        sum += __shfl_xor(sum, 16);
        sum += __shfl_xor(sum, 32);
        if (kg == 0) {
            const float coef = tanhf(sum + cb2[0]);
            const int s = ssrc[edge];
            atom_add_f32(&xout[3 * s + 0], srel[edge][0] * coef);
            atom_add_f32(&xout[3 * s + 1], srel[edge][1] * coef);
            atom_add_f32(&xout[3 * s + 2], srel[edge][2] * coef);
        }
    }

    // m_aggr += m_ij: read all 8 LDS dwords first (ILP), then fire pk-atomics
    {
        unsigned int v[8];
        size_t gaddr[8];
#pragma unroll
        for (int it = 0; it < 8; ++it) {
            const int idx = it * 512 + t;
            const int e = idx >> 6;          // 64 dwords (128 bf16) per edge
            const int dw = idx & 63;
            const int ui = (e * 128 + dw * 2) ^ ((e & 7) << 3);
            v[it] = *(const unsigned int*)(sE + ui);
            gaddr[it] = (size_t)ssrc[e] * 128 + dw * 2;
        }
#pragma unroll
        for (int it = 0; it < 8; ++it) atom_pk_bf16(maggr + gaddr[it], v[it]);
    }
}

// ---------------- node ----------------
__global__ __launch_bounds__(256, 4) void node_kernel(
    const float* __restrict__ h, const ushort_t* __restrict__ hb,
    const ushort_t* __restrict__ maggr,
    const ushort_t* __restrict__ n1b, const float* __restrict__ nb1,
    const ushort_t* __restrict__ n2b, const float* __restrict__ nb2,
    const ushort_t* __restrict__ n3b, const float* __restrict__ nb3,
    float* __restrict__ hout) {
    __shared__ ushort_t sE[16384];
    const int t = threadIdx.x;
    const int lane = t & 63;
    const int wid = t >> 6;
    const int r15 = lane & 15;
    const int khi = lane >> 4;
    const int rhi = khi * 4;
    const int fb = wid * 32;
    const int n0 = blockIdx.x * 64;

    // stage [hb[n] | maggr[n]] (raw bf16, 16B chunks)
    const uint4* hb4 = (const uint4*)hb;
    const uint4* mg4 = (const uint4*)maggr;
#pragma unroll
    for (int it = 0; it < 8; ++it) {
        const int idx = it * 256 + t;
        const int e = idx >> 5, c = idx & 31;
        const int n = n0 + e;
        uint4 v = make_uint4(0u, 0u, 0u, 0u);
        if (n < N_NODES) v = (c < 16) ? hb4[(size_t)n * 16 + c] : mg4[(size_t)n * 16 + (c - 16)];
        const int ui = (e * 256 + c * 8) ^ ((e & 7) << 3);
        *(uint4*)(sE + ui) = v;
    }
    __syncthreads();

    // N1: K=256, wave owns 32 feats (2 row-blocks)
    f32x4 acc[2][4];
#pragma unroll
    for (int mi = 0; mi < 2; ++mi)
#pragma unroll
        for (int ni = 0; ni < 4; ++ni) acc[mi][ni] = (f32x4){0.f, 0.f, 0.f, 0.f};
#pragma unroll
    for (int ks = 0; ks < 8; ++ks) {
        const bf16x8 a0 = *(const bf16x8*)(n1b + (fb + r15) * 256 + ks * 32 + khi * 8);
        const bf16x8 a1 = *(const bf16x8*)(n1b + (fb + 16 + r15) * 256 + ks * 32 + khi * 8);
        bf16x8 b[4];
#pragma unroll
        for (int ni = 0; ni < 4; ++ni) {
            const int edge = ni * 16 + r15;
            const int ui = (edge * 256 + ks * 32 + khi * 8) ^ ((edge & 7) << 3);
            b[ni] = *(const bf16x8*)(sE + ui);
        }
#pragma unroll
        for (int ni = 0; ni < 4; ++ni) {
            acc[0][ni] = __builtin_amdgcn_mfma_f32_16x16x32_bf16(a0, b[ni], acc[0][ni], 0, 0, 0);
            acc[1][ni] = __builtin_amdgcn_mfma_f32_16x16x32_bf16(a1, b[ni], acc[1][ni], 0, 0, 0);
        }
    }
    __syncthreads();
    {
        const float4 bb0 = *(const float4*)&nb1[fb + rhi];
        const float4 bb1 = *(const float4*)&nb1[fb + 16 + rhi];
#pragma unroll
        for (int mi = 0; mi < 2; ++mi) {
            const float4 bb = mi ? bb1 : bb0;
#pragma unroll
            for (int ni = 0; ni < 4; ++ni) {
                const int edge = ni * 16 + r15;
                const float v0 = silu_f(acc[mi][ni][0] + bb.x);
                const float v1 = silu_f(acc[mi][ni][1] + bb.y);
                const float v2 = silu_f(acc[mi][ni][2] + bb.z);
                const float v3 = silu_f(acc[mi][ni][3] + bb.w);
                const int ui = (edge * 128 + fb + mi * 16 + rhi) ^ ((edge & 7) << 3);
                *(uint2*)(sE + ui) = make_uint2(pack2(v0, v1), pack2(v2, v3));
            }
        }
    }
    __syncthreads();

    // N2: two 16-feat halves; b[4] loaded before MFMAs
    {
#pragma unroll
        for (int half = 0; half < 2; ++half) {
            f32x4 a2[4];
#pragma unroll
            for (int ni = 0; ni < 4; ++ni) a2[ni] = (f32x4){0.f, 0.f, 0.f, 0.f};
            const int fbh = fb + half * 16;
#pragma unroll
            for (int ks = 0; ks < 4; ++ks) {
                const bf16x8 a0 = *(const bf16x8*)(n2b + (fbh + r15) * 128 + ks * 32 + khi * 8);
                bf16x8 b[4];
#pragma unroll
                for (int ni = 0; ni < 4; ++ni) {
                    const int edge = ni * 16 + r15;
                    const int ui = (edge * 128 + ks * 32 + khi * 8) ^ ((edge & 7) << 3);
                    b[ni] = *(const bf16x8*)(sE + ui);
                }
#pragma unroll
                for (int ni = 0; ni < 4; ++ni)
                    a2[ni] = __builtin_amdgcn_mfma_f32_16x16x32_bf16(a0, b[ni], a2[ni], 0, 0, 0);
            }
            const float4 bb = *(const float4*)&nb2[fbh + rhi];
#pragma unroll
            for (int ni = 0; ni < 4; ++ni) {
                const int edge = ni * 16 + r15;
                const float v0 = silu_f(a2[ni][0] + bb.x);
                const float v1 = silu_f(a2[ni][1] + bb.y);
                const float v2 = silu_f(a2[ni][2] + bb.z);
                const float v3 = silu_f(a2[ni][3] + bb.w);
                const int ui = (8192 + edge * 128 + fbh + rhi) ^ ((edge & 7) << 3);
                *(uint2*)(sE + ui) = make_uint2(pack2(v0, v1), pack2(v2, v3));
            }
        }
    }
    __syncthreads();

    // N3 + residual epilogue straight to global (f32, float4 stores)
    {
        f32x4 a3[2][4];
#pragma unroll
        for (int mi = 0; mi < 2; ++mi)
#pragma unroll
            for (int ni = 0; ni < 4; ++ni) a3[mi][ni] = (f32x4){0.f, 0.f, 0.f, 0.f};
#pragma unroll
        for (int ks = 0; ks < 4; ++ks) {
            const bf16x8 a0 = *(const bf16x8*)(n3b + (fb + r15) * 128 + ks * 32 + khi * 8);
            const bf16x8 a1 = *(const bf16x8*)(n3b + (fb + 16 + r15) * 128 + ks * 32 + khi * 8);
            bf16x8 b[4];
#pragma unroll
            for (int ni = 0; ni < 4; ++ni) {
                const int edge = ni * 16 + r15;
                const int ui = (8192 + edge * 128 + ks * 32 + khi * 8) ^ ((edge & 7) << 3);
                b[ni] = *(const bf16x8*)(sE + ui);
            }
#pragma unroll
            for (int ni = 0; ni < 4; ++ni) {
                a3[0][ni] = __builtin_amdgcn_mfma_f32_16x16x32_bf16(a0, b[ni], a3[0][ni], 0, 0, 0);
                a3[1][ni] = __builtin_amdgcn_mfma_f32_16x16x32_bf16(a1, b[ni], a3[1][ni], 0, 0, 0);
            }
        }
        const float4 bb0 = *(const float4*)&nb3[fb + rhi];
        const float4 bb1 = *(const float4*)&nb3[fb + 16 + rhi];
#pragma unroll
        for (int mi = 0; mi < 2; ++mi) {
            const float4 bb = mi ? bb1 : bb0;
#pragma unroll
            for (int ni = 0; ni < 4; ++ni) {
                const int n = n0 + ni * 16 + r15;
                if (n < N_NODES) {
                    const size_t o = (size_t)n * 128 + fb + mi * 16 + rhi;
                    const float4 hv = *(const float4*)&h[o];
                    float4 ov;
                    ov.x = hv.x + a3[mi][ni][0] + bb.x;
                    ov.y = hv.y + a3[mi][ni][1] + bb.y;
                    ov.z = hv.z + a3[mi][ni][2] + bb.z;
                    ov.w = hv.w + a3[mi][ni][3] + bb.w;
                    *(float4*)&hout[o] = ov;
                }
            }
        }
    }
}

extern "C" void kernel_launch(void* const* d_in, const int* in_sizes, int n_in,
                              void* d_out, int out_size, void* d_ws, size_t ws_size,
                              hipStream_t stream) {
    const float* x   = (const float*)d_in[0];
    const float* h   = (const float*)d_in[1];
    const int*   ei  = (const int*)d_in[2];
    const float* ew1 = (const float*)d_in[3];
    const float* eb1 = (const float*)d_in[4];
    const float* ew2 = (const float*)d_in[5];
    const float* eb2 = (const float*)d_in[6];
    const float* ew3 = (const float*)d_in[7];
    const float* eb3 = (const float*)d_in[8];
    const float* cw1 = (const float*)d_in[9];
    const float* cb1 = (const float*)d_in[10];
    const float* cw2 = (const float*)d_in[11];
    const float* cb2 = (const float*)d_in[12];
    const float* nw1 = (const float*)d_in[13];
    const float* nb1 = (const float*)d_in[14];
    const float* nw2 = (const float*)d_in[15];
    const float* nb2 = (const float*)d_in[16];
    const float* nw3 = (const float*)d_in[17];
    const float* nb3 = (const float*)d_in[18];

    float* out  = (float*)d_out;
    float* xout = out;                       // [50000,3]
    float* hout = out + (size_t)N_NODES * 3; // [50000,128]
    ushort_t* wsu = (ushort_t*)d_ws;

    ushort_t* maggr = wsu + U_MAGGR;
    const ushort_t* hb  = wsu + U_HB;
    const ushort_t* wab = wsu + U_W1B;       // Wab 256x128
    const ushort_t* w2b = wsu + U_W2B;
    const ushort_t* w3b = wsu + U_W3B;
    const ushort_t* c1b = wsu + U_C1B;
    const ushort_t* n1b = wsu + U_N1B;
    const ushort_t* n2b = wsu + U_N2B;
    const ushort_t* n3b = wsu + U_N3B;
    const float* w1d2 = (const float*)(wsu + U_W1D2);

    // AB table (bf16 [N][256] = 25.6 MB) stashed in the hout region of d_out;
    // node_kernel fully overwrites hout afterwards.
    ushort_t* abp = (ushort_t*)hout;

    const long prep_total = 3200000L + 3200000L + 32768 + 3 * 16384 + 32768 + 2 * 16384 + 128 + 150000;
    const int prep_blocks = (int)((prep_total + 255) / 256);
    prep_kernel<<<prep_blocks, 256, 0, stream>>>(x, h, ew1, ew2, ew3, cw1, nw1, nw2, nw3,
                                                 wsu, xout);

    ab_kernel<<<(N_NODES + 63) / 64, 256, 0, stream>>>(hb, wab, eb1, abp);

    edge_kernel<<<N_EDGES / 64, 512, 0, stream>>>(x, abp, ei,
                                                  w1d2, w2b, eb2, w3b, eb3,
                                                  c1b, cb1, cw2, cb2,
                                                  xout, maggr);

    node_kernel<<<(N_NODES + 63) / 64, 256, 0, stream>>>(h, hb, maggr,
                                                         n1b, nb1, n2b, nb2, n3b, nb3,
                                                         hout);
}